// Round 1
// baseline (39.751 us; speedup 1.0000x reference)
//
#include <hip/hip_runtime.h>

#define FD 128   // feature dim
#define NB 1024  // batch
#define NC 16    // classes

// ws layout (floats unless noted):
//   hi  [NB*FD]   = features @ W1[:FD] + b1
//   hj  [NB*FD]   = features @ W1[FD:]
//   cnt [NC] int  = per-class counts
//   lst [NC*NB] int = per-class j indices
// total ~1.11 MB

// K1: hi/hj precompute. 128 blocks x 256 threads; each thread owns
// (row, 4 consecutive d) for both hi and hj. W1 is L1/L2-resident.
__global__ __launch_bounds__(256) void eg_pre(
    const float* __restrict__ f, const float* __restrict__ W1,
    const float* __restrict__ b1, float* __restrict__ hi,
    float* __restrict__ hj, int* __restrict__ cnt)
{
  if (blockIdx.x == 0 && threadIdx.x < NC) cnt[threadIdx.x] = 0;
  const int tid = threadIdx.x;
  const int d4  = (tid & 31) << 2;           // d in {0,4,...,124}
  const int row = blockIdx.x * 8 + (tid >> 5);
  const float* __restrict__ frow = f + row * FD;
  float4 ha = make_float4(0.f, 0.f, 0.f, 0.f);
  float4 hb = make_float4(0.f, 0.f, 0.f, 0.f);
#pragma unroll 4
  for (int k = 0; k < FD; ++k) {
    const float fv = frow[k];
    const float4 wa = *reinterpret_cast<const float4*>(W1 + k * FD + d4);
    const float4 wb = *reinterpret_cast<const float4*>(W1 + (k + FD) * FD + d4);
    ha.x = fmaf(fv, wa.x, ha.x); ha.y = fmaf(fv, wa.y, ha.y);
    ha.z = fmaf(fv, wa.z, ha.z); ha.w = fmaf(fv, wa.w, ha.w);
    hb.x = fmaf(fv, wb.x, hb.x); hb.y = fmaf(fv, wb.y, hb.y);
    hb.z = fmaf(fv, wb.z, hb.z); hb.w = fmaf(fv, wb.w, hb.w);
  }
  const float4 bv = *reinterpret_cast<const float4*>(b1 + d4);
  ha.x += bv.x; ha.y += bv.y; ha.z += bv.z; ha.w += bv.w;
  *reinterpret_cast<float4*>(hi + row * FD + d4) = ha;
  *reinterpret_cast<float4*>(hj + row * FD + d4) = hb;
}

// K2: build per-class index lists. Single 1024-thread block; atomics give
// nondeterministic within-class ORDER, but the output is order-independent
// (each j scatters to a distinct column), so results are deterministic.
__global__ __launch_bounds__(1024) void eg_build(
    const int* __restrict__ labels, int* __restrict__ cnt, int* __restrict__ lst)
{
  const int j = threadIdx.x;
  const int c = labels[j];
  const int pos = atomicAdd(&cnt[c], 1);
  lst[c * NB + pos] = j;
}

// K3: one wave per surviving (i,j) pair. Block = row i (4 waves stride the
// class list). Lanes split d (2 each): coalesced 256B+256B hj-row loads
// (hj is 512 KB -> L2 resident), hi row + w2 L1-hot across slots.
__global__ __launch_bounds__(256) void eg_pairs(
    const float* __restrict__ hi, const float* __restrict__ hj,
    const float* __restrict__ w2, const float* __restrict__ b2,
    const int* __restrict__ labels, const int* __restrict__ cnt,
    const int* __restrict__ lst, float* __restrict__ out)
{
  const int i = blockIdx.x;
  const int c = labels[i];
  const int n = cnt[c];
  const int lane = threadIdx.x & 63;
  const int wv = threadIdx.x >> 6;
  const float h0 = hi[i * FD + lane];
  const float h1 = hi[i * FD + lane + 64];
  const float w0 = w2[lane];
  const float w1 = w2[lane + 64];
  const float bb = b2[0];
  for (int s = wv; s < n; s += 4) {
    const int j = lst[c * NB + s];
    if (j == i) continue;  // off-diagonal mask
    float a = fmaxf(h0 + hj[j * FD + lane], 0.f) * w0 +
              fmaxf(h1 + hj[j * FD + lane + 64], 0.f) * w1;
#pragma unroll
    for (int m = 32; m; m >>= 1) a += __shfl_xor(a, m, 64);
    if (lane == 0)
      out[(size_t)i * NB + j] = 1.f / (1.f + __expf(-(a + bb)));
  }
}

extern "C" void kernel_launch(void* const* d_in, const int* in_sizes, int n_in,
                              void* d_out, int out_size, void* d_ws, size_t ws_size,
                              hipStream_t stream) {
  const float* f      = (const float*)d_in[0];
  const int*   labels = (const int*)d_in[1];
  const float* W1     = (const float*)d_in[2];
  const float* b1     = (const float*)d_in[3];
  const float* w2     = (const float*)d_in[4];
  const float* b2     = (const float*)d_in[5];
  float* out = (float*)d_out;

  float* hi = (float*)d_ws;
  float* hj = hi + NB * FD;
  int*   cnt = (int*)(hj + NB * FD);
  int*   lst = cnt + NC;

  // Unmasked elements must be exactly 0 every call (harness poisons once,
  // never re-poisons between replays).
  hipMemsetAsync(d_out, 0, (size_t)NB * NB * sizeof(float), stream);

  eg_pre<<<NB / 8, 256, 0, stream>>>(f, W1, b1, hi, hj, cnt);
  eg_build<<<1, NB, 0, stream>>>(labels, cnt, lst);
  eg_pairs<<<NB, 256, 0, stream>>>(hi, hj, w2, b2, labels, cnt, lst, out);
}

// Round 2
// 30.952 us; speedup vs baseline: 1.2843x; 1.2843x over previous
//
#include <hip/hip_runtime.h>

#define FD 128   // feature dim
#define NB 1024  // batch
#define NC 16    // classes

// ws layout (floats unless noted):
//   hi  [NB*FD]   = features @ W1[:FD] + b1
//   hj  [NB*FD]   = features @ W1[FD:]
//   cnt [NC] int  = per-class counts
//   lst [NC*NB] int = per-class j indices

// K1: hi/hj precompute. 128 blocks x 256 threads; each thread owns
// (row, 4 consecutive d) for both hi and hj. W1 (128 KB) is L2-resident.
__global__ __launch_bounds__(256) void eg_pre(
    const float* __restrict__ f, const float* __restrict__ W1,
    const float* __restrict__ b1, float* __restrict__ hi,
    float* __restrict__ hj, int* __restrict__ cnt)
{
  if (blockIdx.x == 0 && threadIdx.x < NC) cnt[threadIdx.x] = 0;
  const int tid = threadIdx.x;
  const int d4  = (tid & 31) << 2;           // d in {0,4,...,124}
  const int row = blockIdx.x * 8 + (tid >> 5);
  const float* __restrict__ frow = f + row * FD;
  float4 ha = make_float4(0.f, 0.f, 0.f, 0.f);
  float4 hb = make_float4(0.f, 0.f, 0.f, 0.f);
#pragma unroll 4
  for (int k = 0; k < FD; ++k) {
    const float fv = frow[k];
    const float4 wa = *reinterpret_cast<const float4*>(W1 + k * FD + d4);
    const float4 wb = *reinterpret_cast<const float4*>(W1 + (k + FD) * FD + d4);
    ha.x = fmaf(fv, wa.x, ha.x); ha.y = fmaf(fv, wa.y, ha.y);
    ha.z = fmaf(fv, wa.z, ha.z); ha.w = fmaf(fv, wa.w, ha.w);
    hb.x = fmaf(fv, wb.x, hb.x); hb.y = fmaf(fv, wb.y, hb.y);
    hb.z = fmaf(fv, wb.z, hb.z); hb.w = fmaf(fv, wb.w, hb.w);
  }
  const float4 bv = *reinterpret_cast<const float4*>(b1 + d4);
  ha.x += bv.x; ha.y += bv.y; ha.z += bv.z; ha.w += bv.w;
  *reinterpret_cast<float4*>(hi + row * FD + d4) = ha;
  *reinterpret_cast<float4*>(hj + row * FD + d4) = hb;
}

// K2: build per-class index lists. Atomic order is nondeterministic but the
// result is order-independent (each j scatters to a distinct out column).
__global__ __launch_bounds__(1024) void eg_build(
    const int* __restrict__ labels, int* __restrict__ cnt, int* __restrict__ lst)
{
  const int j = threadIdx.x;
  const int c = labels[j];
  const int pos = atomicAdd(&cnt[c], 1);
  lst[c * NB + pos] = j;
}

// K3: block = output row i. Phase 1: zero own 4 KB row (replaces the 39 us
// fillBufferAligned graph node). Phase 2: 4 waves stride the class list,
// 2 pairs in flight per wave for ILP; lanes split d (2 each), 512 B
// coalesced hj-row loads (hj = 512 KB -> L2-resident).
__global__ __launch_bounds__(256) void eg_pairs(
    const float* __restrict__ hi, const float* __restrict__ hj,
    const float* __restrict__ w2, const float* __restrict__ b2,
    const int* __restrict__ labels, const int* __restrict__ cnt,
    const int* __restrict__ lst, float* __restrict__ out)
{
  const int i = blockIdx.x;
  float* __restrict__ row = out + (size_t)i * NB;

  // Phase 1: zero this block's output row (masked elems must be exactly 0;
  // harness poisons once and never re-poisons between replays).
  *reinterpret_cast<float4*>(row + threadIdx.x * 4) =
      make_float4(0.f, 0.f, 0.f, 0.f);
  __syncthreads();  // vmcnt(0)-drained barrier: zeros ordered before scatters

  const int c = labels[i];
  const int n = cnt[c];
  const int lane = threadIdx.x & 63;
  const int wv = threadIdx.x >> 6;
  const float h0 = hi[i * FD + lane];
  const float h1 = hi[i * FD + lane + 64];
  const float w0 = w2[lane];
  const float w1 = w2[lane + 64];
  const float bb = b2[0];
  const int* __restrict__ cls = lst + c * NB;

  for (int s = wv; s < n; s += 8) {
    const int s1 = s + 4;
    const bool has1 = s1 < n;
    const int j0 = cls[s];
    const int j1 = has1 ? cls[s1] : j0;
    float a0 = fmaxf(h0 + hj[j0 * FD + lane], 0.f) * w0 +
               fmaxf(h1 + hj[j0 * FD + lane + 64], 0.f) * w1;
    float a1 = fmaxf(h0 + hj[j1 * FD + lane], 0.f) * w0 +
               fmaxf(h1 + hj[j1 * FD + lane + 64], 0.f) * w1;
#pragma unroll
    for (int m = 32; m; m >>= 1) {
      a0 += __shfl_xor(a0, m, 64);
      a1 += __shfl_xor(a1, m, 64);
    }
    if (lane == 0) {
      if (j0 != i) row[j0] = 1.f / (1.f + __expf(-(a0 + bb)));
      if (has1 && j1 != i) row[j1] = 1.f / (1.f + __expf(-(a1 + bb)));
    }
  }
}

extern "C" void kernel_launch(void* const* d_in, const int* in_sizes, int n_in,
                              void* d_out, int out_size, void* d_ws, size_t ws_size,
                              hipStream_t stream) {
  const float* f      = (const float*)d_in[0];
  const int*   labels = (const int*)d_in[1];
  const float* W1     = (const float*)d_in[2];
  const float* b1     = (const float*)d_in[3];
  const float* w2     = (const float*)d_in[4];
  const float* b2     = (const float*)d_in[5];
  float* out = (float*)d_out;

  float* hi = (float*)d_ws;
  float* hj = hi + NB * FD;
  int*   cnt = (int*)(hj + NB * FD);
  int*   lst = cnt + NC;

  eg_pre<<<NB / 8, 256, 0, stream>>>(f, W1, b1, hi, hj, cnt);
  eg_build<<<1, NB, 0, stream>>>(labels, cnt, lst);
  eg_pairs<<<NB, 256, 0, stream>>>(hi, hj, w2, b2, labels, cnt, lst, out);
}